// Round 16
// baseline (159.090 us; speedup 1.0000x reference)
//
#include <hip/hip_runtime.h>
#include <math.h>

#define Hn 80
#define Wn 80
#define HWn 6400

typedef unsigned short u16;
typedef __attribute__((ext_vector_type(8))) short s16x8;
typedef __attribute__((ext_vector_type(4))) float f32x4;

// A&S 7.1.26 erf (|err| <= 1.5e-7), branch-free: cheaper than libm erff.
__device__ __forceinline__ float gelu_exact(float v) {
  float x = fabsf(v) * 0.70710678118654752f;
  float t = 1.f / (1.f + 0.3275911f * x);
  float p = t * (0.254829592f + t * (-0.284496736f + t * (1.421413741f +
            t * (-1.453152027f + t * 1.061405429f))));
  float erfa = 1.f - p * __expf(-x * x);
  float erfv = copysignf(erfa, v);
  return 0.5f * v * (1.f + erfv);
}
__device__ __forceinline__ u16 f2bf(float x) {
  unsigned u = __float_as_uint(x);
  return (u16)((u + 0x7fffu + ((u >> 16) & 1u)) >> 16);
}
__device__ __forceinline__ float bf2f(u16 h) {
  return __uint_as_float(((unsigned)h) << 16);
}
typedef __attribute__((address_space(1))) const unsigned int* gptr_t;
typedef __attribute__((address_space(3))) unsigned int* lptr_t;
__device__ __forceinline__ void gld16(const void* g, void* l) {
  __builtin_amdgcn_global_load_lds((gptr_t)g, (lptr_t)l, 16, 0, 0);
}
__device__ __forceinline__ void ld16h(const u16* p, float* f) {
  uint4 a = *(const uint4*)p;
  uint4 c = *(const uint4*)(p + 8);
  unsigned w[8] = {a.x, a.y, a.z, a.w, c.x, c.y, c.z, c.w};
  #pragma unroll
  for (int j = 0; j < 8; ++j) {
    f[2 * j]     = __uint_as_float(w[j] << 16);
    f[2 * j + 1] = __uint_as_float(w[j] & 0xffff0000u);
  }
}
__device__ __forceinline__ uint2 pack4bf(float4 v) {
  return make_uint2((unsigned)f2bf(v.x) | ((unsigned)f2bf(v.y) << 16),
                    (unsigned)f2bf(v.z) | ((unsigned)f2bf(v.w) << 16));
}

// ---------------- LN (block-1 input) + fused weight-prep (x>=100, y==0) ----------------
__global__ __launch_bounds__(256) void lnprep_k(const float* __restrict__ in,
    const float* __restrict__ gw, const float* __restrict__ gb, u16* __restrict__ outv,
    const float* __restrict__ q0w, const float* __restrict__ q0b,
    const float* __restrict__ q1w, const float* __restrict__ q1b,
    const float* __restrict__ projw, const float* __restrict__ f1w_1,
    const float* __restrict__ f2w_1, const float* __restrict__ pww,
    const float* __restrict__ f1w_2, const float* __restrict__ f2w_2,
    u16* Wq, float* Bq, u16* Wp, u16* Wf1a, u16* Wf2a, u16* Wpw, u16* Wf1b, u16* Wf2b) {
  if (blockIdx.x >= 100) {
    if (blockIdx.y != 0) return;
    int t = (blockIdx.x - 100) * 256 + threadIdx.x;   // 162 blocks -> t < 41472
    if (t >= 40960) {
      int i = t - 40960;
      if (i < 384) {
        int sel = i >> 7, c = i & 127;
        Bq[i] = ((c >> 4) < 6 ? q0b : q1b)[sel * 128 + c];
      }
      return;
    }
    int e = t * 4;
    if (e < 49152) {
      int r = e >> 7, ic = e & 127;
      int sel = r >> 7, c = r & 127;
      const float* src = ((c >> 4) < 6 ? q0w : q1w) + (size_t)(sel * 128 + c) * 128 + ic;
      *(uint2*)(Wq + e) = pack4bf(*(const float4*)src);
      return;
    }
    e -= 49152;
    if (e < 16384) { *(uint2*)(Wp + e) = pack4bf(*(const float4*)(projw + e)); return; }
    e -= 16384;
    if (e < 24576) { *(uint2*)(Wf1a + e) = pack4bf(*(const float4*)(f1w_1 + e)); return; }
    e -= 24576;
    if (e < 16384) {
      int oc = e >> 7, ic = e & 127;
      uint2 w = make_uint2(0, 0);
      if (ic < 96) w = pack4bf(*(const float4*)(f2w_1 + oc * 96 + ic));
      *(uint2*)(Wf2a + e) = w;
      return;
    }
    e -= 16384;
    if (e < 16384) { *(uint2*)(Wpw + e) = pack4bf(*(const float4*)(pww + e)); return; }
    e -= 16384;
    if (e < 24576) { *(uint2*)(Wf1b + e) = pack4bf(*(const float4*)(f1w_2 + e)); return; }
    e -= 24576;
    {
      int oc = e >> 7, ic = e & 127;
      uint2 w = make_uint2(0, 0);
      if (ic < 96) w = pack4bf(*(const float4*)(f2w_2 + oc * 96 + ic));
      *(uint2*)(Wf2b + e) = w;
    }
    return;
  }
  __shared__ float sS[4][64];
  __shared__ float sQ[4][64];
  __shared__ unsigned sT[64 * 64];
  const int b = blockIdx.y;
  const int p0 = blockIdx.x * 64;
  const int tid = threadIdx.x;
  const int px = tid & 63;
  const int cg = tid >> 6;
  const float* ip = in + (size_t)b * 128 * HWn + p0 + px;
  float s = 0.f, q = 0.f;
  #pragma unroll 8
  for (int c = cg * 32; c < cg * 32 + 32; ++c) { float v = ip[(size_t)c * HWn]; s += v; q += v * v; }
  sS[cg][px] = s; sQ[cg][px] = q;
  __syncthreads();
  float S = sS[0][px] + sS[1][px] + sS[2][px] + sS[3][px];
  float Q = sQ[0][px] + sQ[1][px] + sQ[2][px] + sQ[3][px];
  float mu = S * (1.f / 128.f);
  float rs = rsqrtf(Q * (1.f / 128.f) - mu * mu + 1e-6f);
  #pragma unroll
  for (int j = 0; j < 16; ++j) {
    int c0 = cg * 32 + 2 * j;
    float v0 = ip[(size_t)c0 * HWn];
    float v1 = ip[(size_t)(c0 + 1) * HWn];
    v0 = (v0 - mu) * rs * gw[c0] + gb[c0];
    v1 = (v1 - mu) * rs * gw[c0 + 1] + gb[c0 + 1];
    int wc = cg * 16 + j;
    sT[px * 64 + (wc ^ (px & 31))] = (unsigned)f2bf(v0) | ((unsigned)f2bf(v1) << 16);
  }
  __syncthreads();
  u16* ob = outv + ((size_t)b * HWn + p0) * 128;
  #pragma unroll
  for (int it = 0; it < 4; ++it) {
    int opx = it * 16 + (tid >> 4);
    int chunk = tid & 15;
    unsigned w[4];
    #pragma unroll
    for (int j = 0; j < 4; ++j)
      w[j] = sT[opx * 64 + ((chunk * 4 + j) ^ (opx & 31))];
    *(uint4*)(ob + (size_t)opx * 128 + chunk * 8) = make_uint4(w[0], w[1], w[2], w[3]);
  }
}

// ---------------- bf16 MFMA GEMM (128px x 64oc) — known-best ----------------
__device__ __forceinline__ s16x8 ldfrag(const u16* s, int row, int gk) {
  return *(const s16x8*)(s + row * 128 + ((gk ^ (row & 7)) << 3));
}

template<int ORIENT, int SPLITQ, int H16>
__global__ __launch_bounds__(256) void gemm_k(
    const u16* __restrict__ Xg, const u16* __restrict__ Wg,
    const float* __restrict__ bias, u16* __restrict__ outH, int OCT) {
  __shared__ u16 sX[128 * 128];
  __shared__ u16 sW[64 * 128];
  const int tid = threadIdx.x, lane = tid & 63, wv = tid >> 6;
  const int b = blockIdx.y;
  const int px0 = blockIdx.x * 128;
  const int oc0 = blockIdx.z * 64;
  const u16* xb = Xg + ((size_t)b * HWn + px0) * 128;
  const u16* wb = Wg + (size_t)oc0 * 128;
  #pragma unroll
  for (int i = 0; i < 8; ++i) {
    int o16 = (wv * 8 + i) * 64 + lane;
    int r = o16 >> 4, g = o16 & 15;
    gld16(xb + (size_t)r * 128 + ((g ^ (r & 7)) << 3), (char*)sX + (size_t)(wv * 8 + i) * 1024);
  }
  #pragma unroll
  for (int i = 0; i < 4; ++i) {
    int o16 = (wv * 4 + i) * 64 + lane;
    int r = o16 >> 4, g = o16 & 15;
    gld16(wb + (size_t)r * 128 + ((g ^ (r & 7)) << 3), (char*)sW + (size_t)(wv * 4 + i) * 1024);
  }
  __syncthreads();
  const int l15 = lane & 15, l4 = lane >> 4;
  if (ORIENT == 0) {
    f32x4 acc[4][2] = {};
    #pragma unroll
    for (int ks = 0; ks < 4; ++ks) {
      int gk = ks * 4 + l4;
      s16x8 a[4], bb[2];
      #pragma unroll
      for (int mi = 0; mi < 4; ++mi) a[mi] = ldfrag(sW, mi * 16 + l15, gk);
      #pragma unroll
      for (int ni = 0; ni < 2; ++ni) bb[ni] = ldfrag(sX, wv * 32 + ni * 16 + l15, gk);
      #pragma unroll
      for (int mi = 0; mi < 4; ++mi)
        #pragma unroll
        for (int ni = 0; ni < 2; ++ni)
          acc[mi][ni] = __builtin_amdgcn_mfma_f32_16x16x32_bf16(a[mi], bb[ni], acc[mi][ni], 0, 0, 0);
    }
    #pragma unroll
    for (int mi = 0; mi < 4; ++mi) {
      #pragma unroll
      for (int rr = 0; rr < 4; ++rr) {
        int oc = oc0 + mi * 16 + l4 * 4 + rr;
        float bv = bias[oc];
        #pragma unroll
        for (int ni = 0; ni < 2; ++ni) {
          size_t idx = ((size_t)b * OCT + oc) * HWn + px0 + wv * 32 + ni * 16 + l15;
          outH[idx] = f2bf(acc[mi][ni][rr] + bv);
        }
      }
    }
  } else {
    f32x4 acc[2][4] = {};
    #pragma unroll
    for (int ks = 0; ks < 4; ++ks) {
      int gk = ks * 4 + l4;
      s16x8 a[2], bb[4];
      #pragma unroll
      for (int mi = 0; mi < 2; ++mi) a[mi] = ldfrag(sX, wv * 32 + mi * 16 + l15, gk);
      #pragma unroll
      for (int ni = 0; ni < 4; ++ni) bb[ni] = ldfrag(sW, ni * 16 + l15, gk);
      #pragma unroll
      for (int mi = 0; mi < 2; ++mi)
        #pragma unroll
        for (int ni = 0; ni < 4; ++ni)
          acc[mi][ni] = __builtin_amdgcn_mfma_f32_16x16x32_bf16(a[mi], bb[ni], acc[mi][ni], 0, 0, 0);
    }
    #pragma unroll
    for (int ni = 0; ni < 4; ++ni) {
      int oc = oc0 + ni * 16 + l15;
      float bv = bias[oc];
      #pragma unroll
      for (int mi = 0; mi < 2; ++mi) {
        #pragma unroll
        for (int rr = 0; rr < 4; ++rr) {
          int px = px0 + wv * 32 + mi * 16 + l4 * 4 + rr;
          float v = acc[mi][ni][rr] + bv;
          u16 hv = f2bf(v);
          int sel = oc >> 7, c = oc & 127;
          int head = c >> 4, d = c & 15;
          outH[((((size_t)sel * 8 + head) * 4 + b) * HWn + px) * 16 + d] = hv;
        }
      }
    }
  }
}

// ---------------- residual GEMM 32px x 128oc + fused LN epilogue (800 blocks) ----------------
template<int EPI>
__global__ __launch_bounds__(256) void gemm64_k(
    const u16* __restrict__ Xg, const u16* __restrict__ Wg,
    const float* __restrict__ bias, const float* __restrict__ resid,
    float* __restrict__ outF, u16* __restrict__ outLN, float2* __restrict__ stats,
    const float* __restrict__ gw, const float* __restrict__ gb) {
  __shared__ u16 sX[32 * 128];    // 8 KB
  __shared__ u16 sW[128 * 128];   // 32 KB
  const int tid = threadIdx.x, lane = tid & 63, wv = tid >> 6;
  const int b = blockIdx.y;
  const int px0 = blockIdx.x * 32;
  const u16* xb = Xg + ((size_t)b * HWn + px0) * 128;
  #pragma unroll
  for (int i = 0; i < 2; ++i) {
    int o16 = i * 256 + tid;
    int r = o16 >> 4, g = o16 & 15;
    gld16(xb + (size_t)r * 128 + ((g ^ (r & 7)) << 3), (char*)sX + (size_t)o16 * 16);
  }
  #pragma unroll
  for (int i = 0; i < 8; ++i) {
    int o16 = i * 256 + tid;
    int r = o16 >> 4, g = o16 & 15;
    gld16(Wg + (size_t)r * 128 + ((g ^ (r & 7)) << 3), (char*)sW + (size_t)o16 * 16);
  }
  __syncthreads();
  const int l15 = lane & 15, l4 = lane >> 4;
  const int h = wv >> 1, oh = wv & 1;
  f32x4 acc[4] = {};
  #pragma unroll
  for (int ks = 0; ks < 4; ++ks) {
    int gk = ks * 4 + l4;
    s16x8 bb = ldfrag(sX, h * 16 + l15, gk);
    #pragma unroll
    for (int mi = 0; mi < 4; ++mi) {
      s16x8 a = ldfrag(sW, oh * 64 + mi * 16 + l15, gk);
      acc[mi] = __builtin_amdgcn_mfma_f32_16x16x32_bf16(a, bb, acc[mi], 0, 0, 0);
    }
  }
  const int pxg = px0 + h * 16 + l15;
  float v[4][4];
  float s = 0.f, q = 0.f;
  #pragma unroll
  for (int mi = 0; mi < 4; ++mi) {
    #pragma unroll
    for (int rr = 0; rr < 4; ++rr) {
      int oc = oh * 64 + mi * 16 + l4 * 4 + rr;
      float t = acc[mi][rr] + bias[oc];
      t += resid[((size_t)b * 128 + oc) * HWn + pxg];
      v[mi][rr] = t;
      s += t;
      q = fmaf(t, t, q);
      outF[((size_t)b * 128 + oc) * HWn + pxg] = t;
    }
  }
  if (EPI == 0) return;
  s += __shfl_xor(s, 16); s += __shfl_xor(s, 32);
  q += __shfl_xor(q, 16); q += __shfl_xor(q, 32);
  float* sRed = (float*)sX;
  __syncthreads();
  if (lane < 16) {
    sRed[(h * 2 + oh) * 16 + l15] = s;
    sRed[64 + (h * 2 + oh) * 16 + l15] = q;
  }
  __syncthreads();
  float S = sRed[(h * 2) * 16 + l15] + sRed[(h * 2 + 1) * 16 + l15];
  float Q = sRed[64 + (h * 2) * 16 + l15] + sRed[64 + (h * 2 + 1) * 16 + l15];
  float mu = S * (1.f / 128.f);
  float rs = rsqrtf(Q * (1.f / 128.f) - mu * mu + 1e-6f);
  if (EPI == 1) {
    u16* lp = outLN + ((size_t)b * HWn + pxg) * 128;
    #pragma unroll
    for (int mi = 0; mi < 4; ++mi) {
      int oc0 = oh * 64 + mi * 16 + l4 * 4;
      unsigned lo = (unsigned)f2bf((v[mi][0] - mu) * rs * gw[oc0] + gb[oc0])
                  | ((unsigned)f2bf((v[mi][1] - mu) * rs * gw[oc0 + 1] + gb[oc0 + 1]) << 16);
      unsigned hi = (unsigned)f2bf((v[mi][2] - mu) * rs * gw[oc0 + 2] + gb[oc0 + 2])
                  | ((unsigned)f2bf((v[mi][3] - mu) * rs * gw[oc0 + 3] + gb[oc0 + 3]) << 16);
      *(uint2*)(lp + oc0) = make_uint2(lo, hi);
    }
  } else {
    if (oh == 0 && lane < 16) stats[(size_t)b * HWn + pxg] = make_float2(mu, rs);
  }
}

// ---------------- neighborhood attention: K staged in LDS, V direct from L2 ----------------
template<int KS, int DIL>
__device__ __forceinline__ void natt_body(const u16* __restrict__ qkv,
    u16* __restrict__ out, u16* __restrict__ sK,
    int b, int h, int ty0, int tx0, int tid, int ly, int lx) {
  constexpr int HALO = DIL * (KS / 2);
  constexpr int D = 16 + 2 * HALO;
  const u16* Qb = qkv + (((size_t)h * 4 + b) * HWn) * 16;
  const u16* Kb = qkv + ((((size_t)8 + h) * 4 + b) * HWn) * 16;
  const u16* Vb = qkv + ((((size_t)16 + h) * 4 + b) * HWn) * 16;
  for (int i = tid; i < D * D * 2; i += 256) {
    int pxi = i >> 1, half = i & 1;
    int ey = pxi / D, ex = pxi - ey * D;
    int gy = ty0 - HALO + ey, gx = tx0 - HALO + ex;
    uint4 kv = make_uint4(0, 0, 0, 0);
    if (gy >= 0 && gy < Hn && gx >= 0 && gx < Wn)
      kv = *(const uint4*)(Kb + (size_t)(gy * Wn + gx) * 16 + half * 8);
    *(uint4*)(sK + pxi * 16 + half * 8) = kv;
  }
  const int p = (ty0 + ly) * Wn + tx0 + lx;
  float qv[16];
  ld16h(Qb + (size_t)p * 16, qv);
  #pragma unroll
  for (int d = 0; d < 16; ++d) qv[d] *= 0.25f;
  __syncthreads();
  constexpr int L = KS * KS;
  float lg[L];
  #pragma unroll
  for (int i = 0; i < KS; ++i) {
    #pragma unroll
    for (int j = 0; j < KS; ++j) {
      float kvv[16];
      ld16h(sK + (size_t)((ly + i * DIL) * D + lx + j * DIL) * 16, kvv);
      float a = 0.f;
      #pragma unroll
      for (int d = 0; d < 16; ++d) a = fmaf(qv[d], kvv[d], a);
      lg[i * KS + j] = a;
    }
  }
  float mx = lg[0];
  #pragma unroll
  for (int l = 1; l < L; ++l) mx = fmaxf(mx, lg[l]);
  float sum = 0.f;
  #pragma unroll
  for (int l = 0; l < L; ++l) { float e = __expf(lg[l] - mx); lg[l] = e; sum += e; }
  float inv = 1.f / sum;
  float acc[16];
  #pragma unroll
  for (int d = 0; d < 16; ++d) acc[d] = 0.f;
  #pragma unroll
  for (int i = 0; i < KS; ++i) {
    #pragma unroll
    for (int j = 0; j < KS; ++j) {
      int yy = ty0 + ly + i * DIL - HALO;
      int xx = tx0 + lx + j * DIL - HALO;
      if (yy >= 0 && yy < Hn && xx >= 0 && xx < Wn) {
        float vv[16];
        ld16h(Vb + (size_t)(yy * Wn + xx) * 16, vv);
        float wl = lg[i * KS + j] * inv;
        #pragma unroll
        for (int d = 0; d < 16; ++d) acc[d] = fmaf(wl, vv[d], acc[d]);
      }
    }
  }
  unsigned wst[8];
  #pragma unroll
  for (int j = 0; j < 8; ++j)
    wst[j] = (unsigned)f2bf(acc[2 * j]) | ((unsigned)f2bf(acc[2 * j + 1]) << 16);
  u16* op = out + ((size_t)b * HWn + p) * 128 + h * 16;
  *(uint4*)op = make_uint4(wst[0], wst[1], wst[2], wst[3]);
  *(uint4*)(op + 8) = make_uint4(wst[4], wst[5], wst[6], wst[7]);
}

__global__ __launch_bounds__(256) void natt_k(const u16* __restrict__ qkv,
                                              u16* __restrict__ out) {
  __shared__ u16 sK[24 * 24 * 16];   // 18.4 KB (K only)
  const int b = blockIdx.y, h = blockIdx.z;
  const int tile = blockIdx.x;
  const int ty0 = (tile / 5) * 16, tx0 = (tile % 5) * 16;
  const int tid = threadIdx.x;
  const int ly = tid >> 4, lx = tid & 15;
  if (h < 6) natt_body<3, 1>(qkv, out, sK, b, h, ty0, tx0, tid, ly, lx);
  else       natt_body<5, 2>(qkv, out, sK, b, h, ty0, tx0, tid, ly, lx);
}

// ---------------- msconvstar star v6: two-phase batch stage (reg ILP), ONE sync ----------------
template<int R>
__device__ __forceinline__ float dw_from_lds(const float* __restrict__ s, int ly, int lx,
                                             const float* __restrict__ w, float bv) {
  constexpr int PD = 16 + 2 * R + 1;
  float center = s[(ly + R) * PD + (lx + R)];
  float acc = bv;
  #pragma unroll
  for (int i = 0; i < 2 * R + 1; ++i)
    #pragma unroll
    for (int j = 0; j < 2 * R + 1; ++j)
      acc = fmaf(w[i * (2 * R + 1) + j], s[(ly + i) * PD + (lx + j)], acc);
  return center + acc;
}

template<int R1, int R2>
__device__ __forceinline__ void star_all2(const u16* __restrict__ hb,
    const float* __restrict__ w0, const float* __restrict__ b0,
    const float* __restrict__ w1, const float* __restrict__ b1,
    const float* __restrict__ w2, const float* __restrict__ b2,
    float* __restrict__ s1, float* __restrict__ s2,
    int z, int ty0, int tx0, int tid, int ly, int lx, unsigned* __restrict__ res) {
  constexpr int D1 = 16 + 2 * R1, PD1 = D1 + 1, N1 = D1 * D1, SZ1 = D1 * PD1;
  constexpr int D2 = 16 + 2 * R2, PD2 = D2 + 1, N2 = D2 * D2, SZ2 = D2 * PD2;
  // phase 1: ALL loads issued into registers (independent -> single latency window)
  float r1[8][2], r2[8][2];
  #pragma unroll
  for (int p = 0; p < 8; ++p) {
    #pragma unroll
    for (int k = 0; k < 2; ++k) {
      int i = tid + k * 256;
      if (R1 > 0 && i < N1) {
        int ey = i / D1, ex = i - ey * D1;
        int gy = ty0 - R1 + ey, gx = tx0 - R1 + ex;
        float v = 0.f;
        if (gy >= 0 && gy < Hn && gx >= 0 && gx < Wn)
          v = bf2f(hb[(size_t)(z * 8 + p) * HWn + gy * Wn + gx]);
        r1[p][k] = v;
      }
      if (i < N2) {
        int ey = i / D2, ex = i - ey * D2;
        int gy = ty0 - R2 + ey, gx = tx0 - R2 + ex;
        float v = 0.f;
        if (gy >= 0 && gy < Hn && gx >= 0 && gx < Wn)
          v = bf2f(hb[(size_t)(z * 8 + 96 + p) * HWn + gy * Wn + gx]);
        r2[p][k] = v;
      }
    }
  }
  // phase 2: write to LDS
  #pragma unroll
  for (int p = 0; p < 8; ++p) {
    #pragma unroll
    for (int k = 0; k < 2; ++k) {
      int i = tid + k * 256;
      if (R1 > 0 && i < N1) {
        int ey = i / D1, ex = i - ey * D1;
        s1[p * SZ1 + ey * PD1 + ex] = r1[p][k];
      }
      if (i < N2) {
        int ey = i / D2, ex = i - ey * D2;
        s2[p * SZ2 + ey * PD2 + ex] = r2[p][k];
      }
    }
  }
  __syncthreads();
  // phase 3: 8 pair-computes, zero barriers
  #pragma unroll 1
  for (int pi = 0; pi < 8; ++pi) {
    int c1 = z * 8 + pi;
    int c2 = c1 + 96;
    float h1;
    if constexpr (R1 == 0) {
      float cen = bf2f(hb[(size_t)c1 * HWn + (ty0 + ly) * Wn + tx0 + lx]);
      h1 = cen + fmaf(cen, w0[c1], b0[c1]);
    } else {
      h1 = dw_from_lds<R1>(s1 + pi * SZ1, ly, lx, w1 + (c1 - 64) * 9, b1[c1 - 64]);
    }
    float h2;
    if constexpr (R2 == 1) {
      h2 = dw_from_lds<1>(s2 + pi * SZ2, ly, lx, w1 + (c2 - 64) * 9, b1[c2 - 64]);
    } else {
      h2 = dw_from_lds<2>(s2 + pi * SZ2, ly, lx, w2 + (c2 - 128) * 25, b2[c2 - 128]);
    }
    u16 gv = f2bf(gelu_exact(h1) * h2);
    if (pi & 1) res[pi >> 1] |= ((unsigned)gv) << 16;
    else        res[pi >> 1] = (unsigned)gv;
  }
}

__global__ __launch_bounds__(256) void star_k(const u16* __restrict__ hbuf,
    const float* __restrict__ w0, const float* __restrict__ b0,
    const float* __restrict__ w1, const float* __restrict__ b1,
    const float* __restrict__ w2, const float* __restrict__ b2,
    u16* __restrict__ g) {
  __shared__ float sBuf[8 * (18 * 19) + 8 * (20 * 21)];   // 24.4 KB worst case
  const int b = blockIdx.y, z = blockIdx.z;
  const int tile = blockIdx.x;
  const int ty0 = (tile / 5) * 16, tx0 = (tile % 5) * 16;
  const int tid = threadIdx.x;
  const int ly = tid >> 4, lx = tid & 15;
  const u16* hb = hbuf + (size_t)b * 192 * HWn;
  unsigned res[4];
  if (z < 4)
    star_all2<0, 1>(hb, w0, b0, w1, b1, w2, b2, sBuf, sBuf, z, ty0, tx0, tid, ly, lx, res);
  else if (z < 8)
    star_all2<0, 2>(hb, w0, b0, w1, b1, w2, b2, sBuf, sBuf, z, ty0, tx0, tid, ly, lx, res);
  else
    star_all2<1, 2>(hb, w0, b0, w1, b1, w2, b2, sBuf, sBuf + 8 * (18 * 19), z, ty0, tx0, tid, ly, lx, res);
  const int px = (ty0 + ly) * Wn + tx0 + lx;
  *(uint4*)(g + ((size_t)b * HWn + px) * 128 + z * 8) = make_uint4(res[0], res[1], res[2], res[3]);
  // MUST zero pad cols 96..127 (round-5 lesson: garbage bf16 can be Inf/NaN; 0*Inf=NaN).
  if (z < 4)
    *(uint4*)(g + ((size_t)b * HWn + px) * 128 + 96 + z * 8) = make_uint4(0, 0, 0, 0);
}

// ---------------- fused block-3 (known-good) ----------------
__global__ __launch_bounds__(256) void dwgf_k(const float* __restrict__ xin,
    const float2* __restrict__ st,
    const float* __restrict__ gw, const float* __restrict__ gb,
    const float* __restrict__ w1, const float* __restrict__ b1,
    const float* __restrict__ w2, const float* __restrict__ b2,
    u16* __restrict__ out) {
  __shared__ float sA[22 * 23];
  __shared__ float sB[20 * 21];
  __shared__ float sMu[22 * 22];
  __shared__ float sRs[22 * 22];
  const int b = blockIdx.y, z = blockIdx.z;
  const int tile = blockIdx.x;
  const int ty0 = (tile / 5) * 16, tx0 = (tile % 5) * 16;
  const int tid = threadIdx.x;
  const int ly = tid >> 4, lx = tid & 15;
  #pragma unroll
  for (int i = tid; i < 22 * 22; i += 256) {
    int ey = i / 22, ex = i - ey * 22;
    int gy = ty0 - 3 + ey, gx = tx0 - 3 + ex;
    float2 s = make_float2(0.f, 0.f);
    if (gy >= 0 && gy < Hn && gx >= 0 && gx < Wn) s = st[(size_t)b * HWn + gy * Wn + gx];
    sMu[i] = s.x; sRs[i] = s.y;
  }
  const float* xb = xin + (size_t)b * 128 * HWn;
  unsigned res[4];
  #pragma unroll 1
  for (int ci = 0; ci < 8; ++ci) {
    int c = z * 8 + ci;
    const float* xp = xb + (size_t)c * HWn;
    float gwc = gw[c], gbc = gb[c];
    __syncthreads();
    #pragma unroll
    for (int i = tid; i < 22 * 22; i += 256) {
      int ey = i / 22, ex = i - ey * 22;
      int gy = ty0 - 3 + ey, gx = tx0 - 3 + ex;
      float v = 0.f;
      if (gy >= 0 && gy < Hn && gx >= 0 && gx < Wn)
        v = (xp[gy * Wn + gx] - sMu[i]) * sRs[i] * gwc + gbc;
      sA[ey * 23 + ex] = v;
    }
    __syncthreads();
    #pragma unroll
    for (int j = tid; j < 20 * 20; j += 256) {
      int by = j / 20, bx = j - by * 20;
      int gy = ty0 - 2 + by, gx = tx0 - 2 + bx;
      float r = 0.f;
      if (gy >= 0 && gy < Hn && gx >= 0 && gx < Wn) {
        float acc = b1[c];
        #pragma unroll
        for (int di = 0; di < 3; ++di)
          #pragma unroll
          for (int dj = 0; dj < 3; ++dj)
            acc = fmaf(w1[c * 9 + di * 3 + dj], sA[(by + di) * 23 + (bx + dj)], acc);
        r = gelu_exact(acc);
      }
      sB[by * 21 + bx] = r;
    }
    __syncthreads();
    float acc = b2[c];
    #pragma unroll
    for (int di = 0; di < 3; ++di)
      #pragma unroll
      for (int dj = 0; dj < 3; ++dj)
        acc = fmaf(w2[c * 9 + di * 3 + dj], sB[(ly + 2 * di) * 21 + (lx + 2 * dj)], acc);
    float r = gelu_exact(acc);
    u16 gv = f2bf(r);
    if (ci & 1) res[ci >> 1] |= ((unsigned)gv) << 16;
    else        res[ci >> 1] = (unsigned)gv;
  }
  const int px = (ty0 + ly) * Wn + tx0 + lx;
  *(uint4*)(out + ((size_t)b * HWn + px) * 128 + z * 8) = make_uint4(res[0], res[1], res[2], res[3]);
}

// ---------------- launch ----------------
extern "C" void kernel_launch(void* const* d_in, const int* in_sizes, int n_in,
                              void* d_out, int out_size, void* d_ws, size_t ws_size,
                              hipStream_t stream) {
  (void)in_sizes; (void)n_in; (void)out_size; (void)ws_size;
  const float* x      = (const float*)d_in[0];
  const float* n1w    = (const float*)d_in[1];
  const float* n1b    = (const float*)d_in[2];
  const float* n2w    = (const float*)d_in[3];
  const float* n2b    = (const float*)d_in[4];
  const float* n3w    = (const float*)d_in[5];
  const float* n3b    = (const float*)d_in[6];
  const float* n4w    = (const float*)d_in[7];
  const float* n4b    = (const float*)d_in[8];
  const float* qkv0w  = (const float*)d_in[9];
  const float* qkv0b  = (const float*)d_in[10];
  const float* qkv1w  = (const float*)d_in[11];
  const float* qkv1b  = (const float*)d_in[12];
  const float* projw  = (const float*)d_in[13];
  const float* projb  = (const float*)d_in[14];
  const float* m1fc1w = (const float*)d_in[15];
  const float* m1fc1b = (const float*)d_in[16];
  const float* m1dw0w = (const float*)d_in[17];
  const float* m1dw0b = (const float*)d_in[18];
  const float* m1dw1w = (const float*)d_in[19];
  const float* m1dw1b = (const float*)d_in[20];
  const float* m1dw2w = (const float*)d_in[21];
  const float* m1dw2b = (const float*)d_in[22];
  const float* m1fc2w = (const float*)d_in[23];
  const float* m1fc2b = (const float*)d_in[24];
  const float* smadw0w = (const float*)d_in[25];
  const float* smadw0b = (const float*)d_in[26];
  const float* smadw1w = (const float*)d_in[27];
  const float* smadw1b = (const float*)d_in[28];
  const float* smapww  = (const float*)d_in[29];
  const float* smapwb  = (const float*)d_in[30];
  const float* m2fc1w = (const float*)d_in[31];
  const float* m2fc1b = (const float*)d_in[32];
  const float* m2dw0w = (const float*)d_in[33];
  const float* m2dw0b = (const float*)d_in[34];
  const float* m2dw1w = (const float*)d_in[35];
  const float* m2dw1b = (const float*)d_in[36];
  const float* m2dw2w = (const float*)d_in[37];
  const float* m2dw2b = (const float*)d_in[38];
  const float* m2fc2w = (const float*)d_in[39];
  const float* m2fc2b = (const float*)d_in[40];

  float* out = (float*)d_out;
  char* wsb = (char*)d_ws;
  u16*  QKV = (u16*)(wsb + 0);           // 19,660,800 B  [sel][h][b][px][16]
  u16*  Hb16 = (u16*)(wsb + 0);          // 9,830,400 B   [b][192][6400] bf16 (reuse)
  u16*  LNo = (u16*)(wsb + 19660800);    // 6,553,600 B   [b][px][128]
  u16*  ATT = (u16*)(wsb + 26214400);    // 6,553,600 B   (also G)
  u16*  T2  = (u16*)(wsb + 32768000);    // 6,553,600 B
  char* wp = wsb + 39321600;
  u16* Wq    = (u16*)wp;  wp += 98304;
  u16* Wproj = (u16*)wp;  wp += 32768;
  u16* Wf1a  = (u16*)wp;  wp += 49152;
  u16* Wf2a  = (u16*)wp;  wp += 32768;
  u16* Wpw   = (u16*)wp;  wp += 32768;
  u16* Wf1b  = (u16*)wp;  wp += 49152;
  u16* Wf2b  = (u16*)wp;  wp += 32768;
  float* Bq  = (float*)wp; wp += 2048;
  float2* Stats = (float2*)wp;           // 204,800 B

  dim3 blk(256);

  // ---- Block 1: neighborhood attention (LN + weight-prep fused in one dispatch) ----
  lnprep_k<<<dim3(262, 4), blk, 0, stream>>>(x, n1w, n1b, LNo,
      qkv0w, qkv0b, qkv1w, qkv1b, projw, m1fc1w, m1fc2w, smapww, m2fc1w, m2fc2w,
      Wq, Bq, Wproj, Wf1a, Wf2a, Wpw, Wf1b, Wf2b);
  gemm_k<1, 1, 0><<<dim3(50, 4, 6), blk, 0, stream>>>(LNo, Wq, Bq, QKV, 384);
  natt_k<<<dim3(25, 4, 8), blk, 0, stream>>>(QKV, ATT);
  gemm64_k<1><<<dim3(200, 4), blk, 0, stream>>>(ATT, Wproj, projb, x, out, LNo, nullptr, n2w, n2b);

  // ---- Block 2: msconvstar (m1) ----
  gemm_k<0, 0, 1><<<dim3(50, 4, 3), blk, 0, stream>>>(LNo, Wf1a, m1fc1b, Hb16, 192);
  star_k<<<dim3(25, 4, 12), blk, 0, stream>>>(Hb16, m1dw0w, m1dw0b, m1dw1w, m1dw1b, m1dw2w, m1dw2b, ATT);
  gemm64_k<2><<<dim3(200, 4), blk, 0, stream>>>(ATT, Wf2a, m1fc2b, out, out, nullptr, Stats, nullptr, nullptr);

  // ---- Block 3: cascaded sparse ----
  dwgf_k<<<dim3(25, 4, 16), blk, 0, stream>>>(out, Stats, n3w, n3b,
                                              smadw0w, smadw0b, smadw1w, smadw1b, T2);
  gemm64_k<1><<<dim3(200, 4), blk, 0, stream>>>(T2, Wpw, smapwb, out, out, LNo, nullptr, n4w, n4b);

  // ---- Block 4: msconvstar (m2) ----
  gemm_k<0, 0, 1><<<dim3(50, 4, 3), blk, 0, stream>>>(LNo, Wf1b, m2fc1b, Hb16, 192);
  star_k<<<dim3(25, 4, 12), blk, 0, stream>>>(Hb16, m2dw0w, m2dw0b, m2dw1w, m2dw1b, m2dw2w, m2dw2b, ATT);
  gemm64_k<0><<<dim3(200, 4), blk, 0, stream>>>(ATT, Wf2b, m2fc2b, out, out, nullptr, nullptr, nullptr, nullptr);
}

// Round 17
// 151.553 us; speedup vs baseline: 1.0497x; 1.0497x over previous
//
#include <hip/hip_runtime.h>
#include <math.h>

#define Hn 80
#define Wn 80
#define HWn 6400

typedef unsigned short u16;
typedef __attribute__((ext_vector_type(8))) short s16x8;
typedef __attribute__((ext_vector_type(4))) float f32x4;

// A&S 7.1.26 erf (|err| <= 1.5e-7), branch-free: cheaper than libm erff.
__device__ __forceinline__ float gelu_exact(float v) {
  float x = fabsf(v) * 0.70710678118654752f;
  float t = 1.f / (1.f + 0.3275911f * x);
  float p = t * (0.254829592f + t * (-0.284496736f + t * (1.421413741f +
            t * (-1.453152027f + t * 1.061405429f))));
  float erfa = 1.f - p * __expf(-x * x);
  float erfv = copysignf(erfa, v);
  return 0.5f * v * (1.f + erfv);
}
__device__ __forceinline__ u16 f2bf(float x) {
  unsigned u = __float_as_uint(x);
  return (u16)((u + 0x7fffu + ((u >> 16) & 1u)) >> 16);
}
__device__ __forceinline__ float bf2f(u16 h) {
  return __uint_as_float(((unsigned)h) << 16);
}
typedef __attribute__((address_space(1))) const unsigned int* gptr_t;
typedef __attribute__((address_space(3))) unsigned int* lptr_t;
__device__ __forceinline__ void gld16(const void* g, void* l) {
  __builtin_amdgcn_global_load_lds((gptr_t)g, (lptr_t)l, 16, 0, 0);
}
__device__ __forceinline__ void ld16h(const u16* p, float* f) {
  uint4 a = *(const uint4*)p;
  uint4 c = *(const uint4*)(p + 8);
  unsigned w[8] = {a.x, a.y, a.z, a.w, c.x, c.y, c.z, c.w};
  #pragma unroll
  for (int j = 0; j < 8; ++j) {
    f[2 * j]     = __uint_as_float(w[j] << 16);
    f[2 * j + 1] = __uint_as_float(w[j] & 0xffff0000u);
  }
}
__device__ __forceinline__ uint2 pack4bf(float4 v) {
  return make_uint2((unsigned)f2bf(v.x) | ((unsigned)f2bf(v.y) << 16),
                    (unsigned)f2bf(v.z) | ((unsigned)f2bf(v.w) << 16));
}

// ---------------- LN (block-1 input) + fused weight-prep (x>=100, y==0) ----------------
__global__ __launch_bounds__(256) void lnprep_k(const float* __restrict__ in,
    const float* __restrict__ gw, const float* __restrict__ gb, u16* __restrict__ outv,
    const float* __restrict__ q0w, const float* __restrict__ q0b,
    const float* __restrict__ q1w, const float* __restrict__ q1b,
    const float* __restrict__ projw, const float* __restrict__ f1w_1,
    const float* __restrict__ f2w_1, const float* __restrict__ pww,
    const float* __restrict__ f1w_2, const float* __restrict__ f2w_2,
    u16* Wq, float* Bq, u16* Wp, u16* Wf1a, u16* Wf2a, u16* Wpw, u16* Wf1b, u16* Wf2b) {
  if (blockIdx.x >= 100) {
    if (blockIdx.y != 0) return;
    int t = (blockIdx.x - 100) * 256 + threadIdx.x;   // 162 blocks -> t < 41472
    if (t >= 40960) {
      int i = t - 40960;
      if (i < 384) {
        int sel = i >> 7, c = i & 127;
        Bq[i] = ((c >> 4) < 6 ? q0b : q1b)[sel * 128 + c];
      }
      return;
    }
    int e = t * 4;
    if (e < 49152) {
      int r = e >> 7, ic = e & 127;
      int sel = r >> 7, c = r & 127;
      const float* src = ((c >> 4) < 6 ? q0w : q1w) + (size_t)(sel * 128 + c) * 128 + ic;
      *(uint2*)(Wq + e) = pack4bf(*(const float4*)src);
      return;
    }
    e -= 49152;
    if (e < 16384) { *(uint2*)(Wp + e) = pack4bf(*(const float4*)(projw + e)); return; }
    e -= 16384;
    if (e < 24576) { *(uint2*)(Wf1a + e) = pack4bf(*(const float4*)(f1w_1 + e)); return; }
    e -= 24576;
    if (e < 16384) {
      int oc = e >> 7, ic = e & 127;
      uint2 w = make_uint2(0, 0);
      if (ic < 96) w = pack4bf(*(const float4*)(f2w_1 + oc * 96 + ic));
      *(uint2*)(Wf2a + e) = w;
      return;
    }
    e -= 16384;
    if (e < 16384) { *(uint2*)(Wpw + e) = pack4bf(*(const float4*)(pww + e)); return; }
    e -= 16384;
    if (e < 24576) { *(uint2*)(Wf1b + e) = pack4bf(*(const float4*)(f1w_2 + e)); return; }
    e -= 24576;
    {
      int oc = e >> 7, ic = e & 127;
      uint2 w = make_uint2(0, 0);
      if (ic < 96) w = pack4bf(*(const float4*)(f2w_2 + oc * 96 + ic));
      *(uint2*)(Wf2b + e) = w;
    }
    return;
  }
  __shared__ float sS[4][64];
  __shared__ float sQ[4][64];
  __shared__ unsigned sT[64 * 64];
  const int b = blockIdx.y;
  const int p0 = blockIdx.x * 64;
  const int tid = threadIdx.x;
  const int px = tid & 63;
  const int cg = tid >> 6;
  const float* ip = in + (size_t)b * 128 * HWn + p0 + px;
  float s = 0.f, q = 0.f;
  #pragma unroll 8
  for (int c = cg * 32; c < cg * 32 + 32; ++c) { float v = ip[(size_t)c * HWn]; s += v; q += v * v; }
  sS[cg][px] = s; sQ[cg][px] = q;
  __syncthreads();
  float S = sS[0][px] + sS[1][px] + sS[2][px] + sS[3][px];
  float Q = sQ[0][px] + sQ[1][px] + sQ[2][px] + sQ[3][px];
  float mu = S * (1.f / 128.f);
  float rs = rsqrtf(Q * (1.f / 128.f) - mu * mu + 1e-6f);
  #pragma unroll
  for (int j = 0; j < 16; ++j) {
    int c0 = cg * 32 + 2 * j;
    float v0 = ip[(size_t)c0 * HWn];
    float v1 = ip[(size_t)(c0 + 1) * HWn];
    v0 = (v0 - mu) * rs * gw[c0] + gb[c0];
    v1 = (v1 - mu) * rs * gw[c0 + 1] + gb[c0 + 1];
    int wc = cg * 16 + j;
    sT[px * 64 + (wc ^ (px & 31))] = (unsigned)f2bf(v0) | ((unsigned)f2bf(v1) << 16);
  }
  __syncthreads();
  u16* ob = outv + ((size_t)b * HWn + p0) * 128;
  #pragma unroll
  for (int it = 0; it < 4; ++it) {
    int opx = it * 16 + (tid >> 4);
    int chunk = tid & 15;
    unsigned w[4];
    #pragma unroll
    for (int j = 0; j < 4; ++j)
      w[j] = sT[opx * 64 + ((chunk * 4 + j) ^ (opx & 31))];
    *(uint4*)(ob + (size_t)opx * 128 + chunk * 8) = make_uint4(w[0], w[1], w[2], w[3]);
  }
}

// ---------------- bf16 MFMA GEMM (128px x 64oc) — known-best ----------------
__device__ __forceinline__ s16x8 ldfrag(const u16* s, int row, int gk) {
  return *(const s16x8*)(s + row * 128 + ((gk ^ (row & 7)) << 3));
}

template<int ORIENT, int SPLITQ, int H16>
__global__ __launch_bounds__(256) void gemm_k(
    const u16* __restrict__ Xg, const u16* __restrict__ Wg,
    const float* __restrict__ bias, u16* __restrict__ outH, int OCT) {
  __shared__ u16 sX[128 * 128];
  __shared__ u16 sW[64 * 128];
  const int tid = threadIdx.x, lane = tid & 63, wv = tid >> 6;
  const int b = blockIdx.y;
  const int px0 = blockIdx.x * 128;
  const int oc0 = blockIdx.z * 64;
  const u16* xb = Xg + ((size_t)b * HWn + px0) * 128;
  const u16* wb = Wg + (size_t)oc0 * 128;
  #pragma unroll
  for (int i = 0; i < 8; ++i) {
    int o16 = (wv * 8 + i) * 64 + lane;
    int r = o16 >> 4, g = o16 & 15;
    gld16(xb + (size_t)r * 128 + ((g ^ (r & 7)) << 3), (char*)sX + (size_t)(wv * 8 + i) * 1024);
  }
  #pragma unroll
  for (int i = 0; i < 4; ++i) {
    int o16 = (wv * 4 + i) * 64 + lane;
    int r = o16 >> 4, g = o16 & 15;
    gld16(wb + (size_t)r * 128 + ((g ^ (r & 7)) << 3), (char*)sW + (size_t)(wv * 4 + i) * 1024);
  }
  __syncthreads();
  const int l15 = lane & 15, l4 = lane >> 4;
  if (ORIENT == 0) {
    f32x4 acc[4][2] = {};
    #pragma unroll
    for (int ks = 0; ks < 4; ++ks) {
      int gk = ks * 4 + l4;
      s16x8 a[4], bb[2];
      #pragma unroll
      for (int mi = 0; mi < 4; ++mi) a[mi] = ldfrag(sW, mi * 16 + l15, gk);
      #pragma unroll
      for (int ni = 0; ni < 2; ++ni) bb[ni] = ldfrag(sX, wv * 32 + ni * 16 + l15, gk);
      #pragma unroll
      for (int mi = 0; mi < 4; ++mi)
        #pragma unroll
        for (int ni = 0; ni < 2; ++ni)
          acc[mi][ni] = __builtin_amdgcn_mfma_f32_16x16x32_bf16(a[mi], bb[ni], acc[mi][ni], 0, 0, 0);
    }
    #pragma unroll
    for (int mi = 0; mi < 4; ++mi) {
      #pragma unroll
      for (int rr = 0; rr < 4; ++rr) {
        int oc = oc0 + mi * 16 + l4 * 4 + rr;
        float bv = bias[oc];
        #pragma unroll
        for (int ni = 0; ni < 2; ++ni) {
          size_t idx = ((size_t)b * OCT + oc) * HWn + px0 + wv * 32 + ni * 16 + l15;
          outH[idx] = f2bf(acc[mi][ni][rr] + bv);
        }
      }
    }
  } else {
    f32x4 acc[2][4] = {};
    #pragma unroll
    for (int ks = 0; ks < 4; ++ks) {
      int gk = ks * 4 + l4;
      s16x8 a[2], bb[4];
      #pragma unroll
      for (int mi = 0; mi < 2; ++mi) a[mi] = ldfrag(sX, wv * 32 + mi * 16 + l15, gk);
      #pragma unroll
      for (int ni = 0; ni < 4; ++ni) bb[ni] = ldfrag(sW, ni * 16 + l15, gk);
      #pragma unroll
      for (int mi = 0; mi < 2; ++mi)
        #pragma unroll
        for (int ni = 0; ni < 4; ++ni)
          acc[mi][ni] = __builtin_amdgcn_mfma_f32_16x16x32_bf16(a[mi], bb[ni], acc[mi][ni], 0, 0, 0);
    }
    #pragma unroll
    for (int ni = 0; ni < 4; ++ni) {
      int oc = oc0 + ni * 16 + l15;
      float bv = bias[oc];
      #pragma unroll
      for (int mi = 0; mi < 2; ++mi) {
        #pragma unroll
        for (int rr = 0; rr < 4; ++rr) {
          int px = px0 + wv * 32 + mi * 16 + l4 * 4 + rr;
          float v = acc[mi][ni][rr] + bv;
          u16 hv = f2bf(v);
          int sel = oc >> 7, c = oc & 127;
          int head = c >> 4, d = c & 15;
          outH[((((size_t)sel * 8 + head) * 4 + b) * HWn + px) * 16 + d] = hv;
        }
      }
    }
  }
}

// ---------------- residual GEMM 32px x 128oc + fused LN epilogue (800 blocks) ----------------
template<int EPI>
__global__ __launch_bounds__(256) void gemm64_k(
    const u16* __restrict__ Xg, const u16* __restrict__ Wg,
    const float* __restrict__ bias, const float* __restrict__ resid,
    float* __restrict__ outF, u16* __restrict__ outLN, float2* __restrict__ stats,
    const float* __restrict__ gw, const float* __restrict__ gb) {
  __shared__ u16 sX[32 * 128];    // 8 KB
  __shared__ u16 sW[128 * 128];   // 32 KB
  const int tid = threadIdx.x, lane = tid & 63, wv = tid >> 6;
  const int b = blockIdx.y;
  const int px0 = blockIdx.x * 32;
  const u16* xb = Xg + ((size_t)b * HWn + px0) * 128;
  #pragma unroll
  for (int i = 0; i < 2; ++i) {
    int o16 = i * 256 + tid;
    int r = o16 >> 4, g = o16 & 15;
    gld16(xb + (size_t)r * 128 + ((g ^ (r & 7)) << 3), (char*)sX + (size_t)o16 * 16);
  }
  #pragma unroll
  for (int i = 0; i < 8; ++i) {
    int o16 = i * 256 + tid;
    int r = o16 >> 4, g = o16 & 15;
    gld16(Wg + (size_t)r * 128 + ((g ^ (r & 7)) << 3), (char*)sW + (size_t)o16 * 16);
  }
  __syncthreads();
  const int l15 = lane & 15, l4 = lane >> 4;
  const int h = wv >> 1, oh = wv & 1;
  f32x4 acc[4] = {};
  #pragma unroll
  for (int ks = 0; ks < 4; ++ks) {
    int gk = ks * 4 + l4;
    s16x8 bb = ldfrag(sX, h * 16 + l15, gk);
    #pragma unroll
    for (int mi = 0; mi < 4; ++mi) {
      s16x8 a = ldfrag(sW, oh * 64 + mi * 16 + l15, gk);
      acc[mi] = __builtin_amdgcn_mfma_f32_16x16x32_bf16(a, bb, acc[mi], 0, 0, 0);
    }
  }
  const int pxg = px0 + h * 16 + l15;
  float v[4][4];
  float s = 0.f, q = 0.f;
  #pragma unroll
  for (int mi = 0; mi < 4; ++mi) {
    #pragma unroll
    for (int rr = 0; rr < 4; ++rr) {
      int oc = oh * 64 + mi * 16 + l4 * 4 + rr;
      float t = acc[mi][rr] + bias[oc];
      t += resid[((size_t)b * 128 + oc) * HWn + pxg];
      v[mi][rr] = t;
      s += t;
      q = fmaf(t, t, q);
      outF[((size_t)b * 128 + oc) * HWn + pxg] = t;
    }
  }
  if (EPI == 0) return;
  s += __shfl_xor(s, 16); s += __shfl_xor(s, 32);
  q += __shfl_xor(q, 16); q += __shfl_xor(q, 32);
  float* sRed = (float*)sX;
  __syncthreads();
  if (lane < 16) {
    sRed[(h * 2 + oh) * 16 + l15] = s;
    sRed[64 + (h * 2 + oh) * 16 + l15] = q;
  }
  __syncthreads();
  float S = sRed[(h * 2) * 16 + l15] + sRed[(h * 2 + 1) * 16 + l15];
  float Q = sRed[64 + (h * 2) * 16 + l15] + sRed[64 + (h * 2 + 1) * 16 + l15];
  float mu = S * (1.f / 128.f);
  float rs = rsqrtf(Q * (1.f / 128.f) - mu * mu + 1e-6f);
  if (EPI == 1) {
    u16* lp = outLN + ((size_t)b * HWn + pxg) * 128;
    #pragma unroll
    for (int mi = 0; mi < 4; ++mi) {
      int oc0 = oh * 64 + mi * 16 + l4 * 4;
      unsigned lo = (unsigned)f2bf((v[mi][0] - mu) * rs * gw[oc0] + gb[oc0])
                  | ((unsigned)f2bf((v[mi][1] - mu) * rs * gw[oc0 + 1] + gb[oc0 + 1]) << 16);
      unsigned hi = (unsigned)f2bf((v[mi][2] - mu) * rs * gw[oc0 + 2] + gb[oc0 + 2])
                  | ((unsigned)f2bf((v[mi][3] - mu) * rs * gw[oc0 + 3] + gb[oc0 + 3]) << 16);
      *(uint2*)(lp + oc0) = make_uint2(lo, hi);
    }
  } else {
    if (oh == 0 && lane < 16) stats[(size_t)b * HWn + pxg] = make_float2(mu, rs);
  }
}

// ---------------- neighborhood attention: K staged in LDS, V direct from L2 ----------------
template<int KS, int DIL>
__device__ __forceinline__ void natt_body(const u16* __restrict__ qkv,
    u16* __restrict__ out, u16* __restrict__ sK,
    int b, int h, int ty0, int tx0, int tid, int ly, int lx) {
  constexpr int HALO = DIL * (KS / 2);
  constexpr int D = 16 + 2 * HALO;
  const u16* Qb = qkv + (((size_t)h * 4 + b) * HWn) * 16;
  const u16* Kb = qkv + ((((size_t)8 + h) * 4 + b) * HWn) * 16;
  const u16* Vb = qkv + ((((size_t)16 + h) * 4 + b) * HWn) * 16;
  for (int i = tid; i < D * D * 2; i += 256) {
    int pxi = i >> 1, half = i & 1;
    int ey = pxi / D, ex = pxi - ey * D;
    int gy = ty0 - HALO + ey, gx = tx0 - HALO + ex;
    uint4 kv = make_uint4(0, 0, 0, 0);
    if (gy >= 0 && gy < Hn && gx >= 0 && gx < Wn)
      kv = *(const uint4*)(Kb + (size_t)(gy * Wn + gx) * 16 + half * 8);
    *(uint4*)(sK + pxi * 16 + half * 8) = kv;
  }
  const int p = (ty0 + ly) * Wn + tx0 + lx;
  float qv[16];
  ld16h(Qb + (size_t)p * 16, qv);
  #pragma unroll
  for (int d = 0; d < 16; ++d) qv[d] *= 0.25f;
  __syncthreads();
  constexpr int L = KS * KS;
  float lg[L];
  #pragma unroll
  for (int i = 0; i < KS; ++i) {
    #pragma unroll
    for (int j = 0; j < KS; ++j) {
      float kvv[16];
      ld16h(sK + (size_t)((ly + i * DIL) * D + lx + j * DIL) * 16, kvv);
      float a = 0.f;
      #pragma unroll
      for (int d = 0; d < 16; ++d) a = fmaf(qv[d], kvv[d], a);
      lg[i * KS + j] = a;
    }
  }
  float mx = lg[0];
  #pragma unroll
  for (int l = 1; l < L; ++l) mx = fmaxf(mx, lg[l]);
  float sum = 0.f;
  #pragma unroll
  for (int l = 0; l < L; ++l) { float e = __expf(lg[l] - mx); lg[l] = e; sum += e; }
  float inv = 1.f / sum;
  float acc[16];
  #pragma unroll
  for (int d = 0; d < 16; ++d) acc[d] = 0.f;
  #pragma unroll
  for (int i = 0; i < KS; ++i) {
    #pragma unroll
    for (int j = 0; j < KS; ++j) {
      int yy = ty0 + ly + i * DIL - HALO;
      int xx = tx0 + lx + j * DIL - HALO;
      if (yy >= 0 && yy < Hn && xx >= 0 && xx < Wn) {
        float vv[16];
        ld16h(Vb + (size_t)(yy * Wn + xx) * 16, vv);
        float wl = lg[i * KS + j] * inv;
        #pragma unroll
        for (int d = 0; d < 16; ++d) acc[d] = fmaf(wl, vv[d], acc[d]);
      }
    }
  }
  unsigned wst[8];
  #pragma unroll
  for (int j = 0; j < 8; ++j)
    wst[j] = (unsigned)f2bf(acc[2 * j]) | ((unsigned)f2bf(acc[2 * j + 1]) << 16);
  u16* op = out + ((size_t)b * HWn + p) * 128 + h * 16;
  *(uint4*)op = make_uint4(wst[0], wst[1], wst[2], wst[3]);
  *(uint4*)(op + 8) = make_uint4(wst[4], wst[5], wst[6], wst[7]);
}

__global__ __launch_bounds__(256) void natt_k(const u16* __restrict__ qkv,
                                              u16* __restrict__ out) {
  __shared__ u16 sK[24 * 24 * 16];   // 18.4 KB (K only)
  const int b = blockIdx.y, h = blockIdx.z;
  const int tile = blockIdx.x;
  const int ty0 = (tile / 5) * 16, tx0 = (tile % 5) * 16;
  const int tid = threadIdx.x;
  const int ly = tid >> 4, lx = tid & 15;
  if (h < 6) natt_body<3, 1>(qkv, out, sK, b, h, ty0, tx0, tid, ly, lx);
  else       natt_body<5, 2>(qkv, out, sK, b, h, ty0, tx0, tid, ly, lx);
}

// ---------------- msconvstar star (ping-pong, known-best) ----------------
template<int R>
__device__ __forceinline__ void stage_plane(const u16* __restrict__ plane,
                                            float* __restrict__ s,
                                            int ty0, int tx0, int tid) {
  constexpr int D = 16 + 2 * R, PD = D + 1;
  #pragma unroll
  for (int i = tid; i < D * D; i += 256) {
    int ey = i / D, ex = i - ey * D;
    int gy = ty0 - R + ey, gx = tx0 - R + ex;
    float v = 0.f;
    if (gy >= 0 && gy < Hn && gx >= 0 && gx < Wn) v = bf2f(plane[gy * Wn + gx]);
    s[ey * PD + ex] = v;
  }
}

template<int R>
__device__ __forceinline__ float dw_from_lds(const float* __restrict__ s, int ly, int lx,
                                             const float* __restrict__ w, float bv) {
  constexpr int PD = 16 + 2 * R + 1;
  float center = s[(ly + R) * PD + (lx + R)];
  float acc = bv;
  #pragma unroll
  for (int i = 0; i < 2 * R + 1; ++i)
    #pragma unroll
    for (int j = 0; j < 2 * R + 1; ++j)
      acc = fmaf(w[i * (2 * R + 1) + j], s[(ly + i) * PD + (lx + j)], acc);
  return center + acc;
}

template<int R1, int R2>
__device__ __forceinline__ void star_pairs(const u16* __restrict__ hb,
    const float* __restrict__ w0, const float* __restrict__ b0,
    const float* __restrict__ w1, const float* __restrict__ b1,
    const float* __restrict__ w2, const float* __restrict__ b2,
    float* __restrict__ s1_0, float* __restrict__ s1_1,
    float* __restrict__ s2_0, float* __restrict__ s2_1,
    int z, int ty0, int tx0, int tid, int ly, int lx, unsigned* __restrict__ res) {
  if (R1 > 0) stage_plane<R1>(hb + (size_t)(z * 8) * HWn, s1_0, ty0, tx0, tid);
  stage_plane<R2>(hb + (size_t)(z * 8 + 96) * HWn, s2_0, ty0, tx0, tid);
  __syncthreads();
  #pragma unroll 1
  for (int pi = 0; pi < 8; ++pi) {
    int c1 = z * 8 + pi;
    int c2 = c1 + 96;
    float* s1c = (pi & 1) ? s1_1 : s1_0;
    float* s2c = (pi & 1) ? s2_1 : s2_0;
    if (pi < 7) {
      float* s1n = (pi & 1) ? s1_0 : s1_1;
      float* s2n = (pi & 1) ? s2_0 : s2_1;
      if (R1 > 0) stage_plane<R1>(hb + (size_t)(c1 + 1) * HWn, s1n, ty0, tx0, tid);
      stage_plane<R2>(hb + (size_t)(c2 + 1) * HWn, s2n, ty0, tx0, tid);
    }
    float h1;
    if constexpr (R1 == 0) {
      float cen = bf2f(hb[(size_t)c1 * HWn + (ty0 + ly) * Wn + tx0 + lx]);
      h1 = cen + fmaf(cen, w0[c1], b0[c1]);
    } else {
      h1 = dw_from_lds<R1>(s1c, ly, lx, w1 + (c1 - 64) * 9, b1[c1 - 64]);
    }
    float h2;
    if constexpr (R2 == 1) {
      h2 = dw_from_lds<1>(s2c, ly, lx, w1 + (c2 - 64) * 9, b1[c2 - 64]);
    } else {
      h2 = dw_from_lds<2>(s2c, ly, lx, w2 + (c2 - 128) * 25, b2[c2 - 128]);
    }
    u16 gv = f2bf(gelu_exact(h1) * h2);
    if (pi & 1) res[pi >> 1] |= ((unsigned)gv) << 16;
    else        res[pi >> 1] = (unsigned)gv;
    __syncthreads();
  }
}

__global__ __launch_bounds__(256) void star_k(const u16* __restrict__ hbuf,
    const float* __restrict__ w0, const float* __restrict__ b0,
    const float* __restrict__ w1, const float* __restrict__ b1,
    const float* __restrict__ w2, const float* __restrict__ b2,
    u16* __restrict__ g) {
  __shared__ float s1_0[18 * 19];
  __shared__ float s1_1[18 * 19];
  __shared__ float s2_0[20 * 21];
  __shared__ float s2_1[20 * 21];
  const int b = blockIdx.y, z = blockIdx.z;
  const int tile = blockIdx.x;
  const int ty0 = (tile / 5) * 16, tx0 = (tile % 5) * 16;
  const int tid = threadIdx.x;
  const int ly = tid >> 4, lx = tid & 15;
  const u16* hb = hbuf + (size_t)b * 192 * HWn;
  unsigned res[4];
  if (z < 4)      star_pairs<0, 1>(hb, w0, b0, w1, b1, w2, b2, s1_0, s1_1, s2_0, s2_1, z, ty0, tx0, tid, ly, lx, res);
  else if (z < 8) star_pairs<0, 2>(hb, w0, b0, w1, b1, w2, b2, s1_0, s1_1, s2_0, s2_1, z, ty0, tx0, tid, ly, lx, res);
  else            star_pairs<1, 2>(hb, w0, b0, w1, b1, w2, b2, s1_0, s1_1, s2_0, s2_1, z, ty0, tx0, tid, ly, lx, res);
  const int px = (ty0 + ly) * Wn + tx0 + lx;
  *(uint4*)(g + ((size_t)b * HWn + px) * 128 + z * 8) = make_uint4(res[0], res[1], res[2], res[3]);
  // MUST zero pad cols 96..127 (round-5 lesson: garbage bf16 can be Inf/NaN; 0*Inf=NaN).
  if (z < 4)
    *(uint4*)(g + ((size_t)b * HWn + px) * 128 + 96 + z * 8) = make_uint4(0, 0, 0, 0);
}

// ---------------- fused block-3 (known-good) ----------------
__global__ __launch_bounds__(256) void dwgf_k(const float* __restrict__ xin,
    const float2* __restrict__ st,
    const float* __restrict__ gw, const float* __restrict__ gb,
    const float* __restrict__ w1, const float* __restrict__ b1,
    const float* __restrict__ w2, const float* __restrict__ b2,
    u16* __restrict__ out) {
  __shared__ float sA[22 * 23];
  __shared__ float sB[20 * 21];
  __shared__ float sMu[22 * 22];
  __shared__ float sRs[22 * 22];
  const int b = blockIdx.y, z = blockIdx.z;
  const int tile = blockIdx.x;
  const int ty0 = (tile / 5) * 16, tx0 = (tile % 5) * 16;
  const int tid = threadIdx.x;
  const int ly = tid >> 4, lx = tid & 15;
  #pragma unroll
  for (int i = tid; i < 22 * 22; i += 256) {
    int ey = i / 22, ex = i - ey * 22;
    int gy = ty0 - 3 + ey, gx = tx0 - 3 + ex;
    float2 s = make_float2(0.f, 0.f);
    if (gy >= 0 && gy < Hn && gx >= 0 && gx < Wn) s = st[(size_t)b * HWn + gy * Wn + gx];
    sMu[i] = s.x; sRs[i] = s.y;
  }
  const float* xb = xin + (size_t)b * 128 * HWn;
  unsigned res[4];
  #pragma unroll 1
  for (int ci = 0; ci < 8; ++ci) {
    int c = z * 8 + ci;
    const float* xp = xb + (size_t)c * HWn;
    float gwc = gw[c], gbc = gb[c];
    __syncthreads();
    #pragma unroll
    for (int i = tid; i < 22 * 22; i += 256) {
      int ey = i / 22, ex = i - ey * 22;
      int gy = ty0 - 3 + ey, gx = tx0 - 3 + ex;
      float v = 0.f;
      if (gy >= 0 && gy < Hn && gx >= 0 && gx < Wn)
        v = (xp[gy * Wn + gx] - sMu[i]) * sRs[i] * gwc + gbc;
      sA[ey * 23 + ex] = v;
    }
    __syncthreads();
    #pragma unroll
    for (int j = tid; j < 20 * 20; j += 256) {
      int by = j / 20, bx = j - by * 20;
      int gy = ty0 - 2 + by, gx = tx0 - 2 + bx;
      float r = 0.f;
      if (gy >= 0 && gy < Hn && gx >= 0 && gx < Wn) {
        float acc = b1[c];
        #pragma unroll
        for (int di = 0; di < 3; ++di)
          #pragma unroll
          for (int dj = 0; dj < 3; ++dj)
            acc = fmaf(w1[c * 9 + di * 3 + dj], sA[(by + di) * 23 + (bx + dj)], acc);
        r = gelu_exact(acc);
      }
      sB[by * 21 + bx] = r;
    }
    __syncthreads();
    float acc = b2[c];
    #pragma unroll
    for (int di = 0; di < 3; ++di)
      #pragma unroll
      for (int dj = 0; dj < 3; ++dj)
        acc = fmaf(w2[c * 9 + di * 3 + dj], sB[(ly + 2 * di) * 21 + (lx + 2 * dj)], acc);
    float r = gelu_exact(acc);
    u16 gv = f2bf(r);
    if (ci & 1) res[ci >> 1] |= ((unsigned)gv) << 16;
    else        res[ci >> 1] = (unsigned)gv;
  }
  const int px = (ty0 + ly) * Wn + tx0 + lx;
  *(uint4*)(out + ((size_t)b * HWn + px) * 128 + z * 8) = make_uint4(res[0], res[1], res[2], res[3]);
}

// ---------------- launch ----------------
extern "C" void kernel_launch(void* const* d_in, const int* in_sizes, int n_in,
                              void* d_out, int out_size, void* d_ws, size_t ws_size,
                              hipStream_t stream) {
  (void)in_sizes; (void)n_in; (void)out_size; (void)ws_size;
  const float* x      = (const float*)d_in[0];
  const float* n1w    = (const float*)d_in[1];
  const float* n1b    = (const float*)d_in[2];
  const float* n2w    = (const float*)d_in[3];
  const float* n2b    = (const float*)d_in[4];
  const float* n3w    = (const float*)d_in[5];
  const float* n3b    = (const float*)d_in[6];
  const float* n4w    = (const float*)d_in[7];
  const float* n4b    = (const float*)d_in[8];
  const float* qkv0w  = (const float*)d_in[9];
  const float* qkv0b  = (const float*)d_in[10];
  const float* qkv1w  = (const float*)d_in[11];
  const float* qkv1b  = (const float*)d_in[12];
  const float* projw  = (const float*)d_in[13];
  const float* projb  = (const float*)d_in[14];
  const float* m1fc1w = (const float*)d_in[15];
  const float* m1fc1b = (const float*)d_in[16];
  const float* m1dw0w = (const float*)d_in[17];
  const float* m1dw0b = (const float*)d_in[18];
  const float* m1dw1w = (const float*)d_in[19];
  const float* m1dw1b = (const float*)d_in[20];
  const float* m1dw2w = (const float*)d_in[21];
  const float* m1dw2b = (const float*)d_in[22];
  const float* m1fc2w = (const float*)d_in[23];
  const float* m1fc2b = (const float*)d_in[24];
  const float* smadw0w = (const float*)d_in[25];
  const float* smadw0b = (const float*)d_in[26];
  const float* smadw1w = (const float*)d_in[27];
  const float* smadw1b = (const float*)d_in[28];
  const float* smapww  = (const float*)d_in[29];
  const float* smapwb  = (const float*)d_in[30];
  const float* m2fc1w = (const float*)d_in[31];
  const float* m2fc1b = (const float*)d_in[32];
  const float* m2dw0w = (const float*)d_in[33];
  const float* m2dw0b = (const float*)d_in[34];
  const float* m2dw1w = (const float*)d_in[35];
  const float* m2dw1b = (const float*)d_in[36];
  const float* m2dw2w = (const float*)d_in[37];
  const float* m2dw2b = (const float*)d_in[38];
  const float* m2fc2w = (const float*)d_in[39];
  const float* m2fc2b = (const float*)d_in[40];

  float* out = (float*)d_out;
  char* wsb = (char*)d_ws;
  u16*  QKV = (u16*)(wsb + 0);           // 19,660,800 B  [sel][h][b][px][16]
  u16*  Hb16 = (u16*)(wsb + 0);          // 9,830,400 B   [b][192][6400] bf16 (reuse)
  u16*  LNo = (u16*)(wsb + 19660800);    // 6,553,600 B   [b][px][128]
  u16*  ATT = (u16*)(wsb + 26214400);    // 6,553,600 B   (also G)
  u16*  T2  = (u16*)(wsb + 32768000);    // 6,553,600 B
  char* wp = wsb + 39321600;
  u16* Wq    = (u16*)wp;  wp += 98304;
  u16* Wproj = (u16*)wp;  wp += 32768;
  u16* Wf1a  = (u16*)wp;  wp += 49152;
  u16* Wf2a  = (u16*)wp;  wp += 32768;
  u16* Wpw   = (u16*)wp;  wp += 32768;
  u16* Wf1b  = (u16*)wp;  wp += 49152;
  u16* Wf2b  = (u16*)wp;  wp += 32768;
  float* Bq  = (float*)wp; wp += 2048;
  float2* Stats = (float2*)wp;           // 204,800 B

  dim3 blk(256);

  // ---- Block 1: neighborhood attention (LN + weight-prep fused in one dispatch) ----
  lnprep_k<<<dim3(262, 4), blk, 0, stream>>>(x, n1w, n1b, LNo,
      qkv0w, qkv0b, qkv1w, qkv1b, projw, m1fc1w, m1fc2w, smapww, m2fc1w, m2fc2w,
      Wq, Bq, Wproj, Wf1a, Wf2a, Wpw, Wf1b, Wf2b);
  gemm_k<1, 1, 0><<<dim3(50, 4, 6), blk, 0, stream>>>(LNo, Wq, Bq, QKV, 384);
  natt_k<<<dim3(25, 4, 8), blk, 0, stream>>>(QKV, ATT);
  gemm64_k<1><<<dim3(200, 4), blk, 0, stream>>>(ATT, Wproj, projb, x, out, LNo, nullptr, n2w, n2b);

  // ---- Block 2: msconvstar (m1) ----
  gemm_k<0, 0, 1><<<dim3(50, 4, 3), blk, 0, stream>>>(LNo, Wf1a, m1fc1b, Hb16, 192);
  star_k<<<dim3(25, 4, 12), blk, 0, stream>>>(Hb16, m1dw0w, m1dw0b, m1dw1w, m1dw1b, m1dw2w, m1dw2b, ATT);
  gemm64_k<2><<<dim3(200, 4), blk, 0, stream>>>(ATT, Wf2a, m1fc2b, out, out, nullptr, Stats, nullptr, nullptr);

  // ---- Block 3: cascaded sparse ----
  dwgf_k<<<dim3(25, 4, 16), blk, 0, stream>>>(out, Stats, n3w, n3b,
                                              smadw0w, smadw0b, smadw1w, smadw1b, T2);
  gemm64_k<1><<<dim3(200, 4), blk, 0, stream>>>(T2, Wpw, smapwb, out, out, LNo, nullptr, n4w, n4b);

  // ---- Block 4: msconvstar (m2) ----
  gemm_k<0, 0, 1><<<dim3(50, 4, 3), blk, 0, stream>>>(LNo, Wf1b, m2fc1b, Hb16, 192);
  star_k<<<dim3(25, 4, 12), blk, 0, stream>>>(Hb16, m2dw0w, m2dw0b, m2dw1w, m2dw1b, m2dw2w, m2dw2b, ATT);
  gemm64_k<0><<<dim3(200, 4), blk, 0, stream>>>(ATT, Wf2b, m2fc2b, out, out, nullptr, nullptr, nullptr, nullptr);
}